// Round 8
// baseline (111.160 us; speedup 1.0000x reference)
//
#include <hip/hip_runtime.h>
#include <hip/hip_bf16.h>
#include <math.h>

// Problem constants
#define NB     128          // batches
#define SLEN   4096
#define HID_   1024
#define INDIM_ 272
#define KPAD_  320          // 272 padded to 5*64
#define MFULL  32768
#define N_     1024

typedef __bf16 bf16x8 __attribute__((ext_vector_type(8)));
typedef float  f32x4  __attribute__((ext_vector_type(4)));
typedef __hip_bfloat16 hb;

// ---------------------------------------------------------------- prep ----

// kt<5: W1 (272x1024) f32 -> w1t (1024x320) bf16^T zero-padded
// kt>=5: W2 (1024x1024) f32 -> w2t (1024x1024) bf16^T
__global__ void prep_w(const float* __restrict__ W1, const float* __restrict__ W2,
                       hb* __restrict__ w1t, hb* __restrict__ w2t) {
    __shared__ float tt[64][65];
    const int kt = blockIdx.x;           // 0..20
    const int nt = blockIdx.y;           // 0..15
    const int c = threadIdx.x & 63, r4 = threadIdx.x >> 6;
    if (kt < 5) {
#pragma unroll
        for (int j = 0; j < 16; ++j) {
            int r = j * 4 + r4;
            int k = kt * 64 + r;
            tt[r][c] = (k < INDIM_) ? W1[k * 1024 + nt * 64 + c] : 0.0f;
        }
        __syncthreads();
#pragma unroll
        for (int j = 0; j < 16; ++j) {
            int r = j * 4 + r4;
            w1t[(nt * 64 + r) * KPAD_ + kt * 64 + c] = __float2bfloat16(tt[c][r]);
        }
    } else {
        const int kw = kt - 5;
#pragma unroll
        for (int j = 0; j < 16; ++j) {
            int r = j * 4 + r4;
            tt[r][c] = W2[(kw * 64 + r) * 1024 + nt * 64 + c];
        }
        __syncthreads();
#pragma unroll
        for (int j = 0; j < 16; ++j) {
            int r = j * 4 + r4;
            w2t[(nt * 64 + r) * 1024 + kw * 64 + c] = __float2bfloat16(tt[c][r]);
        }
    }
}

// Per-batch fused: np scan, n_patch output + Mc (block 0), rowmap, compact feat.
__global__ __launch_bounds__(512) void build_feat_c(const float* __restrict__ x,
                                                    const int* __restrict__ lengths,
                                                    const float* __restrict__ pos_table,
                                                    hb* __restrict__ feat,
                                                    unsigned short* __restrict__ rowmap,
                                                    int* __restrict__ mc,
                                                    float* __restrict__ np_out) {
    __shared__ int scan[NB];
    const int b = blockIdx.x, t = threadIdx.x;
    if (t < NB) scan[t] = (lengths[t] + 15) >> 4;
    __syncthreads();
    for (int d = 1; d < NB; d <<= 1) {        // Hillis-Steele inclusive scan
        int v = 0;
        if (t < NB && t >= d) v = scan[t - d];
        __syncthreads();
        if (t < NB && t >= d) scan[t] += v;
        __syncthreads();
    }
    const int L = lengths[b];
    const int np = (L + 15) >> 4;
    const int off = scan[b] - np;
    if (b == 0) {
        if (t < NB) np_out[t] = (float)((lengths[t] + 15) >> 4);
        if (t == 0) *mc = scan[NB - 1];
    }
    for (int p = t; p < np; p += 512)
        rowmap[off + p] = (unsigned short)(b * 256 + p);

    const float* xb = x + (long)b * SLEN * 2;
    const int total = np * 40;
    for (int c = t; c < total; c += 512) {
        const int p = c / 40;
        const int j = c - p * 40;
        const int col = j * 8;
        bf16x8 v;
        if (j < 2) {
#pragma unroll
            for (int e = 0; e < 8; ++e) {
                int tt2 = p * 16 + j * 8 + e;
                int idx = (tt2 < L) ? tt2 : (L - 1);
                v[e] = (__bf16)xb[(long)idx * 2];
            }
        } else if (col < INDIM_) {
            const int q = col - 16;
            const int tt2 = p * 16 + (q >> 4);
            const int pt = (tt2 < L) ? tt2 : SLEN;
            const float* src = pos_table + pt * 16 + (q & 15);
#pragma unroll
            for (int e = 0; e < 8; ++e) v[e] = (__bf16)src[e];
        } else {
            v = (bf16x8)0;
        }
        *(bf16x8*)(feat + (long)(off + p) * KPAD_ + col) = v;
    }
}

// zero all out rows with p >= n_patch(b) — balanced grid-stride
__global__ __launch_bounds__(256) void zero_fill(const int* __restrict__ lengths,
                                                 float* __restrict__ out) {
    for (int r = blockIdx.x; r < MFULL; r += 512) {
        const int b = r >> 8, p = r & 255;
        const int np = (lengths[b] + 15) >> 4;
        if (p >= np)
            *(f32x4*)(out + (long)r * N_ + threadIdx.x * 4) = (f32x4)0.0f;
    }
}

// ---------------------------------------------------------------- GEMM ----

__device__ __forceinline__ void gl_lds16(const hb* g, hb* l) {
    __builtin_amdgcn_global_load_lds(
        (const __attribute__((address_space(1))) unsigned int*)g,
        (__attribute__((address_space(3))) unsigned int*)l, 16, 0, 0);
}

__device__ __forceinline__ float gelu_tanh(float v) {
    float u = 1.5957691216f * v * (1.0f + 0.044715f * v * v);
    float e = __expf(u);
    float th = (e - 1.0f) / (e + 1.0f);
    return 0.5f * v * (1.0f + th);
}

// C(Mc x 1024) = A(Mc x K) @ BT(1024 x K)^T, compact rows.
// 128x128 tile, BK=64, 4 waves (2x2), double-buffered LDS (64 KiB -> 2 blocks/CU).
// Gray quadrants, reg-held B, counted vmcnt(8), runtime-bijective XCD swizzle.
// MODE 0: HOut = bf16(gelu(C+bias)) compact;  MODE 1: FOut[rowmap[r]] = f32(C+bias)
template <int MODE>
__global__ __launch_bounds__(256, 2) void gemm128(const hb* __restrict__ A,
                                                  const hb* __restrict__ BT,
                                                  const float* __restrict__ bias,
                                                  const unsigned short* __restrict__ rowmap,
                                                  const int* __restrict__ mc,
                                                  hb* __restrict__ HOut,
                                                  float* __restrict__ FOut,
                                                  int K, int nt) {
    __shared__ __align__(16) hb Sh[4][8192];   // A: Sh[0..1], B: Sh[2..3]; 64 KiB

    const int Mc = *mc;
    const int nActive = ((Mc + 127) >> 7) * 8;
    const int bid = blockIdx.x;
    if (bid >= nActive) return;
    // bijective chunked XCD swizzle (m204) over the runtime-active grid
    const int q = nActive >> 3, r = nActive & 7;
    const int xcd = bid & 7, idx = bid >> 3;
    const int wg = (xcd < r ? xcd * (q + 1) : r * (q + 1) + (xcd - r) * q) + idx;
    const int bm = wg >> 3;             // bm-major: 8 bn per bm share A-panel on an XCD
    const int bn = wg & 7;

    const int tid = threadIdx.x;
    const int wid = tid >> 6, lane = tid & 63;
    const int wr = wid >> 1, wc = wid & 1;      // 2 x 2 wave grid, 64x64 wave tile
    const int fr = lane & 15, kg = lane >> 4;
    const int swz = (fr & 7) << 4;              // read-side XOR (bytes)

    const long arow0 = (long)bm * 128;
    const int  brow0 = bn * 128;
    const hb* Bbase = BT + (long)brow0 * K;

    // staging: thread -> 16B; pre-swizzled global source, linear LDS dest
    const int srow = tid >> 3;                  // 0..31 (row within 32-row sweep)
    const int sel  = (((tid & 7) << 4) ^ ((srow & 7) << 4)) >> 1;
    const int ldst = tid * 8;

    f32x4 acc[4][4] = {};

    auto stage = [&](int t, int bsel) {
        const int k0 = t << 6;
#pragma unroll
        for (int j = 0; j < 4; ++j) {
            long gr = arow0 + j * 32 + srow;
            if (gr >= Mc) gr = Mc - 1;           // clamp tail rows (dup, discarded)
            gl_lds16(A + gr * K + k0 + sel, &Sh[bsel][j * 2048 + ldst]);
        }
#pragma unroll
        for (int j = 0; j < 4; ++j)
            gl_lds16(Bbase + (long)(j * 32 + srow) * K + k0 + sel,
                     &Sh[2 + bsel][j * 2048 + ldst]);
    };

    stage(0, 0);
    stage(1, 1);
    asm volatile("s_waitcnt vmcnt(8)" ::: "memory");
    asm volatile("s_barrier" ::: "memory");

#define LDA_(dst, Ab, half)                                                  \
    _Pragma("unroll") for (int i = 0; i < 2; ++i)                            \
    _Pragma("unroll") for (int ks = 0; ks < 2; ++ks)                         \
        dst[i][ks] = *(const bf16x8*)((Ab) +                                 \
            (wr * 64 + (half) * 32 + i * 16 + fr) * 128 +                    \
            ((ks * 64 + kg * 16) ^ swz));

#define LDB_(Bb, half)                                                       \
    _Pragma("unroll") for (int jn = 0; jn < 2; ++jn)                         \
    _Pragma("unroll") for (int ks = 0; ks < 2; ++ks)                         \
        Bf[half][jn][ks] = *(const bf16x8*)((Bb) +                           \
            (wc * 64 + (half) * 32 + jn * 16 + fr) * 128 +                   \
            ((ks * 64 + kg * 16) ^ swz));

#define MFMA_QUAD(Aarr, a, b)                                                \
    __builtin_amdgcn_s_setprio(1);                                           \
    _Pragma("unroll") for (int ks = 0; ks < 2; ++ks)                         \
    _Pragma("unroll") for (int i = 0; i < 2; ++i)                            \
    _Pragma("unroll") for (int jn = 0; jn < 2; ++jn)                         \
        acc[(a) * 2 + i][(b) * 2 + jn] =                                     \
            __builtin_amdgcn_mfma_f32_16x16x32_bf16(                         \
                Aarr[i][ks], Bf[b][jn][ks], acc[(a) * 2 + i][(b) * 2 + jn],  \
                0, 0, 0);                                                    \
    __builtin_amdgcn_s_setprio(0);

    for (int t = 0; t < nt; ++t) {
        const char* Ab = (const char*)(&Sh[t & 1][0]);
        const char* Bb = (const char*)(&Sh[2 + (t & 1)][0]);
        bf16x8 A0[2][2], A1[2][2], Bf[2][2][2];

        LDB_(Bb, 0)
        LDA_(A0, Ab, 0)
        MFMA_QUAD(A0, 0, 0)
        LDB_(Bb, 1)
        MFMA_QUAD(A0, 0, 1)
        LDA_(A1, Ab, 1)
        MFMA_QUAD(A1, 1, 1)
        asm volatile("s_waitcnt lgkmcnt(0)" ::: "memory");
        asm volatile("s_barrier" ::: "memory");
        if (t + 2 < nt) stage(t + 2, t & 1);
        MFMA_QUAD(A1, 1, 0)
        if (t + 1 < nt) {
            if (t + 2 < nt) {
                asm volatile("s_waitcnt vmcnt(8)" ::: "memory");
            } else {
                asm volatile("s_waitcnt vmcnt(0)" ::: "memory");
            }
            asm volatile("s_barrier" ::: "memory");
        }
    }

    // ---- LDS-staged epilogue ----
    const int rbase = wr * 64 + kg * 4;
    const int cbase = wc * 64 + fr;
    float bvv[4];
#pragma unroll
    for (int ni = 0; ni < 4; ++ni) bvv[ni] = bias[bn * 128 + cbase + ni * 16];

    if (MODE == 0) {
        hb* Cs = (hb*)Sh;                      // 128 x 128 bf16 tile (32 KiB)
#pragma unroll
        for (int ni = 0; ni < 4; ++ni) {
            const int col = cbase + ni * 16;
#pragma unroll
            for (int mi = 0; mi < 4; ++mi)
#pragma unroll
                for (int r2 = 0; r2 < 4; ++r2) {
                    float v = acc[mi][ni][r2] + bvv[ni];
                    Cs[(rbase + mi * 16 + r2) * 128 + col] = __float2bfloat16(gelu_tanh(v));
                }
        }
        __syncthreads();
#pragma unroll
        for (int c = 0; c < 8; ++c) {
            const int e = (c * 256 + tid) * 8;
            const int row = e >> 7, col = e & 127;
            bf16x8 v = *(const bf16x8*)(Cs + e);
            *(bf16x8*)(HOut + (arow0 + row) * N_ + bn * 128 + col) = v;
        }
    } else {
        float* Cf = (float*)Sh;                // 128 x 128 f32 tile (64 KiB)
#pragma unroll
        for (int ni = 0; ni < 4; ++ni) {
            const int col = cbase + ni * 16;
#pragma unroll
            for (int mi = 0; mi < 4; ++mi)
#pragma unroll
                for (int r2 = 0; r2 < 4; ++r2)
                    Cf[(rbase + mi * 16 + r2) * 128 + col] = acc[mi][ni][r2] + bvv[ni];
        }
        __syncthreads();
#pragma unroll
        for (int c = 0; c < 16; ++c) {
            const int e = (c * 256 + tid) * 4;
            const int row = e >> 7, col = e & 127;
            const long cidx = arow0 + row;
            if (cidx < Mc) {
                f32x4 v = *(const f32x4*)(Cf + e);
                *(f32x4*)(FOut + (long)rowmap[cidx] * N_ + bn * 128 + col) = v;
            }
        }
    }
}

// -------------------------------------------------------------- launch ----

extern "C" void kernel_launch(void* const* d_in, const int* in_sizes, int n_in,
                              void* d_out, int out_size, void* d_ws, size_t ws_size,
                              hipStream_t stream) {
    const float* x         = (const float*)d_in[0];
    const int*   lengths   = (const int*)d_in[1];
    const float* pos_table = (const float*)d_in[2];
    const float* W1        = (const float*)d_in[3];
    const float* b1        = (const float*)d_in[4];
    const float* W2        = (const float*)d_in[5];
    const float* b2        = (const float*)d_in[6];
    float* out = (float*)d_out;

    char* ws = (char*)d_ws;
    hb* w1t                = (hb*)(ws);                        //    655,360 B
    hb* w2t                = (hb*)(ws + 655360);               //  2,097,152 B
    hb* feat               = (hb*)(ws + 2752512);              // 20,971,520 B max
    hb* h                  = (hb*)(ws + 23724032);             // 67,108,864 B max
    unsigned short* rowmap = (unsigned short*)(ws + 90832896); //     65,536 B
    int* mc                = (int*)(ws + 90898432);            //          4 B

    hipLaunchKernelGGL(prep_w, dim3(21, 16), dim3(256), 0, stream, W1, W2, w1t, w2t);
    hipLaunchKernelGGL(build_feat_c, dim3(NB), dim3(512), 0, stream,
                       x, lengths, pos_table, feat, rowmap, mc, out + (long)MFULL * N_);
    hipLaunchKernelGGL(zero_fill, dim3(512), dim3(256), 0, stream, lengths, out);

    // worst-case grids (Mc runtime); excess blocks exit immediately
    hipLaunchKernelGGL((gemm128<0>), dim3(2048), dim3(256), 0, stream,
                       feat, w1t, b1, rowmap, mc, h, nullptr, KPAD_, KPAD_ / 64);
    hipLaunchKernelGGL((gemm128<1>), dim3(2048), dim3(256), 0, stream,
                       h, w2t, b2, rowmap, mc, nullptr, out, HID_, HID_ / 64);
}